// Round 5
// baseline (212.472 us; speedup 1.0000x reference)
//
#include <hip/hip_runtime.h>
#include <type_traits>

namespace {
constexpr int HH = 512;
constexpr int WW = 512;
constexpr int KS = 11;
constexpr int PADR = 5;
constexpr int TH = 32;                 // tile rows per block
constexpr int TW = 64;                 // tile cols per block
constexpr int SLAB = 16;               // rows per slab
constexpr int HC = TW + 2 * PADR;      // 74 columns incl. horizontal halo
constexpr int LPA = 148;               // interleaved pair rows: 74 cols x 2
                                       // floats; 148 % 8 == 4 -> b128 reads
                                       // touch all 32 banks exactly 8x
                                       // (bandwidth-minimal); rows 16B-aligned
constexpr int LPC = 76;                // scalar sxy rows; 76 % 8 == 4, same
constexpr int NTHREADS = 256;
constexpr float SSIM_C1 = 1.0e-4f;     // (0.01*1.0)^2
constexpr float SSIM_C2 = 9.0e-4f;     // (0.03*1.0)^2
}

typedef float v2f __attribute__((ext_vector_type(2)));
typedef float v4f __attribute__((ext_vector_type(4)));
#define LOWP(v)  __builtin_shufflevector(v, v, 0, 1)
#define HIGHP(v) __builtin_shufflevector(v, v, 2, 3)

// R4 structure (verified: VGPR 64, 120us, VALU-issue-bound at 70% VALUBusy)
// + packed-fp32 (VOP3P v_pk_fma_f32) across the statistic pairs:
//  - (sx,sy) and (sxx,syy) are convolved with identical weights -> hold them
//    as <2 x float> so each tap is ONE v_pk_fma_f32 (gfx90a+ legal v2f32).
//    Fallback if the backend doesn't pack = 2 scalar FMAs = exactly R4.
//  - LDS interleaves the pairs so phase-2 ds_read_b128 delivers aligned
//    VGPR pairs directly usable as packed operands.
//  - Phase-1 state stays 10 floats (4 v2f + 2 float) = R4's proven-no-spill
//    size. Weights: read-only v2f pw[6] (kernel is symmetric), same
//    promoted-array class as R4's wt[11].
__global__ __launch_bounds__(NTHREADS, 4) void ssim_fused(
    const float* __restrict__ x, const float* __restrict__ y,
    const float* __restrict__ kern, float* __restrict__ out)
{
    __shared__ __align__(16) float pA[SLAB][LPA];   // (sx,sy) interleaved
    __shared__ __align__(16) float pB_[SLAB][LPA];  // (sxx,syy) interleaved
    __shared__ __align__(16) float pC_[SLAB][LPC];  // sxy scalar
    // total 23808 B -> 4 blocks/CU at launch_bounds(256,4)

    constexpr int tiles_w = WW / TW;         // 8
    constexpr int tiles_h = HH / TH;         // 16
    constexpr int tpp = tiles_w * tiles_h;   // 128 tiles per plane

    const int bid = blockIdx.x;
    const int plane = bid / tpp;
    const int trem = bid - plane * tpp;
    const int tr_idx = trem / tiles_w;
    const int tile_r = tr_idx * TH;
    const int tile_c = (trem - tr_idx * tiles_w) * TW;

    const float* __restrict__ xp = x + (size_t)plane * (HH * WW);
    const float* __restrict__ yp = y + (size_t)plane * (HH * WW);
    float* __restrict__ op = out + (size_t)plane * (HH * WW);

    // 1D gaussian weights (exact for outer products), broadcast pairs.
    // Kernel is symmetric: taps 6..10 mirror 4..0 -> 6 unique weights.
    v2f pw[6];
    {
        const float inv = rsqrtf(kern[5 * KS + 5]);
#pragma unroll
        for (int i = 0; i < 6; ++i) {
            const float w = kern[5 * KS + i] * inv;
            v2f tmp = {w, w};
            pw[i] = tmp;
        }
    }

    const int t = threadIdx.x;
    const bool interior = (tile_r >= PADR) && (tile_r + TH + PADR <= HH) &&
                          (tile_c >= PADR) && (tile_c + TW + PADR <= WW);

    // phase-2 mapping: one 4-wide output group per thread per slab
    const int p2_r = t >> 4;           // 0..15
    const int p2_m = t & 15;           // col group; outputs 4*p2_m .. +3

    auto run_slab = [&](int s0, auto intr_tag) {
        constexpr bool INTR = decltype(intr_tag)::value;
        // ---- phase 1: vertical 11-tap blur into LDS, row pairs, packed.
        for (int i = t; i < (SLAB / 2) * HC; i += NTHREADS) {
            const int r2 = i / HC;
            const int c = i - r2 * HC;
            const int gr = tile_r + s0 + 2 * r2;   // first output row of pair
            const int gc = tile_c + c - PADR;      // input col (maybe OOB)
            v2f uvA = {0.f, 0.f}, qqA = {0.f, 0.f};
            v2f uvB = {0.f, 0.f}, qqB = {0.f, 0.f};
            float xyA = 0.f, xyB = 0.f;
            const float* xq = xp + (gr - PADR) * WW + gc;
            const float* yq = yp + (gr - PADR) * WW + gc;
#pragma unroll
            for (int k = 0; k < KS + 1; ++k) {       // 12 input rows
                float xv, yv;
                if (INTR) {
                    xv = xq[k * WW];
                    yv = yq[k * WW];
                } else {
                    const int rr = gr - PADR + k;
                    const bool ok = (gc >= 0) & (gc < WW) & (rr >= 0) & (rr < HH);
                    xv = 0.f; yv = 0.f;
                    if (ok) {
                        xv = xp[rr * WW + gc];
                        yv = yp[rr * WW + gc];
                    }
                }
                v2f v2 = {xv, yv};
                const v2f q2 = v2 * v2;              // v_pk_mul_f32
                const float xy = xv * yv;
                if (k < KS) {                        // row A taps 0..10
                    const v2f w = pw[k < 6 ? k : 10 - k];
                    uvA += w * v2;                   // v_pk_fma_f32
                    qqA += w * q2;
                    xyA += w.x * xy;
                }
                if (k >= 1) {                        // row B taps 0..10
                    const v2f w = pw[(k - 1) < 6 ? (k - 1) : 11 - k];
                    uvB += w * v2;
                    qqB += w * q2;
                    xyB += w.x * xy;
                }
            }
            const int rA = 2 * r2, rB = 2 * r2 + 1;
            *(v2f*)&pA[rA][2 * c] = uvA;   *(v2f*)&pA[rB][2 * c] = uvB;
            *(v2f*)&pB_[rA][2 * c] = qqA;  *(v2f*)&pB_[rB][2 * c] = qqB;
            pC_[rA][c] = xyA;              pC_[rB][c] = xyB;
        }
        __syncthreads();

        // ---- phase 2: horizontal 11-tap blur (packed) + SSIM.
        // Window pairs P[p] for p=0..13 live in 7 aligned b128 loads;
        // output j uses P[j..j+10] with symmetric weights 0,1,2,3,4,5,4,3,2,1,0.
#define PCONV(R0, R1, R2, R3, a0, a1, a2, a3, a4, a5, a6)                       \
    R0 += pw[0]*LOWP(a0); R0 += pw[1]*HIGHP(a0); R0 += pw[2]*LOWP(a1);          \
    R0 += pw[3]*HIGHP(a1); R0 += pw[4]*LOWP(a2); R0 += pw[5]*HIGHP(a2);         \
    R0 += pw[4]*LOWP(a3); R0 += pw[3]*HIGHP(a3); R0 += pw[2]*LOWP(a4);          \
    R0 += pw[1]*HIGHP(a4); R0 += pw[0]*LOWP(a5);                                \
    R1 += pw[0]*HIGHP(a0); R1 += pw[1]*LOWP(a1); R1 += pw[2]*HIGHP(a1);         \
    R1 += pw[3]*LOWP(a2); R1 += pw[4]*HIGHP(a2); R1 += pw[5]*LOWP(a3);          \
    R1 += pw[4]*HIGHP(a3); R1 += pw[3]*LOWP(a4); R1 += pw[2]*HIGHP(a4);         \
    R1 += pw[1]*LOWP(a5); R1 += pw[0]*HIGHP(a5);                                \
    R2 += pw[0]*LOWP(a1); R2 += pw[1]*HIGHP(a1); R2 += pw[2]*LOWP(a2);          \
    R2 += pw[3]*HIGHP(a2); R2 += pw[4]*LOWP(a3); R2 += pw[5]*HIGHP(a3);         \
    R2 += pw[4]*LOWP(a4); R2 += pw[3]*HIGHP(a4); R2 += pw[2]*LOWP(a5);          \
    R2 += pw[1]*HIGHP(a5); R2 += pw[0]*LOWP(a6);                                \
    R3 += pw[0]*HIGHP(a1); R3 += pw[1]*LOWP(a2); R3 += pw[2]*HIGHP(a2);         \
    R3 += pw[3]*LOWP(a3); R3 += pw[4]*HIGHP(a3); R3 += pw[5]*LOWP(a4);          \
    R3 += pw[4]*HIGHP(a4); R3 += pw[3]*LOWP(a5); R3 += pw[2]*HIGHP(a5);         \
    R3 += pw[1]*LOWP(a6); R3 += pw[0]*HIGHP(a6);

#define SCONV(R, S0, S1, S2, S3, S4, S5, S6, S7, S8, S9, S10)                   \
    R += pw[0].x*S0; R += pw[1].x*S1; R += pw[2].x*S2; R += pw[3].x*S3;         \
    R += pw[4].x*S4; R += pw[5].x*S5; R += pw[4].x*S6; R += pw[3].x*S7;         \
    R += pw[2].x*S8; R += pw[1].x*S9; R += pw[0].x*S10;

        v2f rUV0 = {0.f, 0.f}, rUV1 = {0.f, 0.f}, rUV2 = {0.f, 0.f}, rUV3 = {0.f, 0.f};
        {
            const float* rowA = &pA[p2_r][8 * p2_m];
            const v4f a0 = *(const v4f*)(rowA + 0);
            const v4f a1 = *(const v4f*)(rowA + 4);
            const v4f a2 = *(const v4f*)(rowA + 8);
            const v4f a3 = *(const v4f*)(rowA + 12);
            const v4f a4 = *(const v4f*)(rowA + 16);
            const v4f a5 = *(const v4f*)(rowA + 20);
            const v4f a6 = *(const v4f*)(rowA + 24);
            PCONV(rUV0, rUV1, rUV2, rUV3, a0, a1, a2, a3, a4, a5, a6)
        }
        v2f rQQ0 = {0.f, 0.f}, rQQ1 = {0.f, 0.f}, rQQ2 = {0.f, 0.f}, rQQ3 = {0.f, 0.f};
        {
            const float* rowB = &pB_[p2_r][8 * p2_m];
            const v4f a0 = *(const v4f*)(rowB + 0);
            const v4f a1 = *(const v4f*)(rowB + 4);
            const v4f a2 = *(const v4f*)(rowB + 8);
            const v4f a3 = *(const v4f*)(rowB + 12);
            const v4f a4 = *(const v4f*)(rowB + 16);
            const v4f a5 = *(const v4f*)(rowB + 20);
            const v4f a6 = *(const v4f*)(rowB + 24);
            PCONV(rQQ0, rQQ1, rQQ2, rQQ3, a0, a1, a2, a3, a4, a5, a6)
        }
        float rC0 = 0.f, rC1 = 0.f, rC2 = 0.f, rC3 = 0.f;
        {
            const float* rowC = &pC_[p2_r][4 * p2_m];
            const v4f c0 = *(const v4f*)(rowC + 0);
            const v4f c1 = *(const v4f*)(rowC + 4);
            const v4f c2 = *(const v4f*)(rowC + 8);
            const v4f c3 = *(const v4f*)(rowC + 12);
            const float e0 = c0.x, e1 = c0.y, e2 = c0.z, e3 = c0.w;
            const float e4 = c1.x, e5 = c1.y, e6 = c1.z, e7 = c1.w;
            const float e8 = c2.x, e9 = c2.y, e10 = c2.z, e11 = c2.w;
            const float e12 = c3.x, e13 = c3.y;
            SCONV(rC0, e0, e1, e2, e3, e4, e5, e6, e7, e8, e9, e10)
            SCONV(rC1, e1, e2, e3, e4, e5, e6, e7, e8, e9, e10, e11)
            SCONV(rC2, e2, e3, e4, e5, e6, e7, e8, e9, e10, e11, e12)
            SCONV(rC3, e3, e4, e5, e6, e7, e8, e9, e10, e11, e12, e13)
        }

        float4 o4;
#pragma unroll
        for (int j = 0; j < 4; ++j) {
            const v2f uvj = (j == 0) ? rUV0 : (j == 1) ? rUV1 : (j == 2) ? rUV2 : rUV3;
            const v2f qqj = (j == 0) ? rQQ0 : (j == 1) ? rQQ1 : (j == 2) ? rQQ2 : rQQ3;
            const float uxy = (j == 0) ? rC0 : (j == 1) ? rC1 : (j == 2) ? rC2 : rC3;
            const float ux = uvj.x, uy = uvj.y;
            const float uxx = qqj.x, uyy = qqj.y;
            const float vx  = uxx - ux * ux;
            const float vy  = uyy - uy * uy;
            const float vxy = uxy - ux * uy;
            const float a1s = 2.f * ux * uy + SSIM_C1;
            const float a2s = 2.f * vxy + SSIM_C2;
            const float b1s = ux * ux + uy * uy + SSIM_C1;
            const float b2s = vx + vy + SSIM_C2;
            (&o4.x)[j] = (a1s * a2s) * __builtin_amdgcn_rcpf(b1s * b2s);
        }
        *(float4*)(op + (size_t)(tile_r + s0 + p2_r) * WW + (tile_c + 4 * p2_m)) = o4;
        __syncthreads();   // LDS reused by next slab
#undef PCONV
#undef SCONV
    };

    if (interior) {
        run_slab(0,    std::true_type{});
        run_slab(SLAB, std::true_type{});
    } else {
        run_slab(0,    std::false_type{});
        run_slab(SLAB, std::false_type{});
    }
}

extern "C" void kernel_launch(void* const* d_in, const int* in_sizes, int n_in,
                              void* d_out, int out_size, void* d_ws, size_t ws_size,
                              hipStream_t stream) {
    const float* x    = (const float*)d_in[0];
    const float* y    = (const float*)d_in[1];
    const float* kern = (const float*)d_in[2];
    float* out = (float*)d_out;

    const int nplanes = in_sizes[0] / (HH * WW);            // 48
    const int nblocks = nplanes * (HH / TH) * (WW / TW);    // 6144

    ssim_fused<<<dim3(nblocks), dim3(NTHREADS), 0, stream>>>(x, y, kern, out);
}

// Round 6
// 203.391 us; speedup vs baseline: 1.0446x; 1.0446x over previous
//
#include <hip/hip_runtime.h>
#include <type_traits>

namespace {
constexpr int HH = 512;
constexpr int WW = 512;
constexpr int KS = 11;
constexpr int PADR = 5;
constexpr int TH = 32;                 // tile rows per block
constexpr int TW = 64;                 // tile cols per block
constexpr int SLAB = 16;               // rows per slab
constexpr int HC = TW + 2 * PADR;      // 74 columns incl. horizontal halo
constexpr int LPA = 148;               // interleaved pair rows: 74 cols x 2
                                       // floats; 148 % 8 == 4 -> b128 reads
                                       // touch all 32 banks exactly 8x
                                       // (bandwidth-minimal); rows 16B-aligned
constexpr int LPC = 76;                // scalar sxy rows; 76 % 8 == 4, same
constexpr int NTHREADS = 256;
constexpr float SSIM_C1 = 1.0e-4f;     // (0.01*1.0)^2
constexpr float SSIM_C2 = 9.0e-4f;     // (0.03*1.0)^2
}

typedef float v2f __attribute__((ext_vector_type(2)));
typedef float v4f __attribute__((ext_vector_type(4)));
#define LOWP(v)  __builtin_shufflevector(v, v, 0, 1)
#define HIGHP(v) __builtin_shufflevector(v, v, 2, 3)

// R5 kernel (verified: VGPR 40, 116us, VALUBusy 48%, occupancy 53%) with ONE
// change: residency 4 -> 6 blocks/CU (__launch_bounds__(256,6)).
// R5 post-mortem: packed fp32 cut VALU-issue time 84->56us but dur only
// 120->116us -- a ~60us bubble floor (barriers + phase-1 592/256=2.31
// load-imbalance tail + load latency) was exposed. Occupancy measured 53%
// == exactly the old launch-bounds cap (4 blocks/CU); VGPR 40 and LDS 24KB
// allow 6 blocks (144KB <= 160KB, VGPR budget 512/6=85 >> 40). More
// co-resident blocks fill the barrier/imbalance bubbles with ready waves.
__global__ __launch_bounds__(NTHREADS, 6) void ssim_fused(
    const float* __restrict__ x, const float* __restrict__ y,
    const float* __restrict__ kern, float* __restrict__ out)
{
    __shared__ __align__(16) float pA[SLAB][LPA];   // (sx,sy) interleaved
    __shared__ __align__(16) float pB_[SLAB][LPA];  // (sxx,syy) interleaved
    __shared__ __align__(16) float pC_[SLAB][LPC];  // sxy scalar
    // total 23808 B -> 6 blocks/CU = 144KB of 160KB LDS

    constexpr int tiles_w = WW / TW;         // 8
    constexpr int tiles_h = HH / TH;         // 16
    constexpr int tpp = tiles_w * tiles_h;   // 128 tiles per plane

    const int bid = blockIdx.x;
    const int plane = bid / tpp;
    const int trem = bid - plane * tpp;
    const int tr_idx = trem / tiles_w;
    const int tile_r = tr_idx * TH;
    const int tile_c = (trem - tr_idx * tiles_w) * TW;

    const float* __restrict__ xp = x + (size_t)plane * (HH * WW);
    const float* __restrict__ yp = y + (size_t)plane * (HH * WW);
    float* __restrict__ op = out + (size_t)plane * (HH * WW);

    // 1D gaussian weights (exact for outer products), broadcast pairs.
    // Kernel is symmetric: taps 6..10 mirror 4..0 -> 6 unique weights.
    v2f pw[6];
    {
        const float inv = rsqrtf(kern[5 * KS + 5]);
#pragma unroll
        for (int i = 0; i < 6; ++i) {
            const float w = kern[5 * KS + i] * inv;
            v2f tmp = {w, w};
            pw[i] = tmp;
        }
    }

    const int t = threadIdx.x;
    const bool interior = (tile_r >= PADR) && (tile_r + TH + PADR <= HH) &&
                          (tile_c >= PADR) && (tile_c + TW + PADR <= WW);

    // phase-2 mapping: one 4-wide output group per thread per slab
    const int p2_r = t >> 4;           // 0..15
    const int p2_m = t & 15;           // col group; outputs 4*p2_m .. +3

    auto run_slab = [&](int s0, auto intr_tag) {
        constexpr bool INTR = decltype(intr_tag)::value;
        // ---- phase 1: vertical 11-tap blur into LDS, row pairs, packed.
        for (int i = t; i < (SLAB / 2) * HC; i += NTHREADS) {
            const int r2 = i / HC;
            const int c = i - r2 * HC;
            const int gr = tile_r + s0 + 2 * r2;   // first output row of pair
            const int gc = tile_c + c - PADR;      // input col (maybe OOB)
            v2f uvA = {0.f, 0.f}, qqA = {0.f, 0.f};
            v2f uvB = {0.f, 0.f}, qqB = {0.f, 0.f};
            float xyA = 0.f, xyB = 0.f;
            const float* xq = xp + (gr - PADR) * WW + gc;
            const float* yq = yp + (gr - PADR) * WW + gc;
#pragma unroll
            for (int k = 0; k < KS + 1; ++k) {       // 12 input rows
                float xv, yv;
                if (INTR) {
                    xv = xq[k * WW];
                    yv = yq[k * WW];
                } else {
                    const int rr = gr - PADR + k;
                    const bool ok = (gc >= 0) & (gc < WW) & (rr >= 0) & (rr < HH);
                    xv = 0.f; yv = 0.f;
                    if (ok) {
                        xv = xp[rr * WW + gc];
                        yv = yp[rr * WW + gc];
                    }
                }
                v2f v2 = {xv, yv};
                const v2f q2 = v2 * v2;              // v_pk_mul_f32
                const float xy = xv * yv;
                if (k < KS) {                        // row A taps 0..10
                    const v2f w = pw[k < 6 ? k : 10 - k];
                    uvA += w * v2;                   // v_pk_fma_f32
                    qqA += w * q2;
                    xyA += w.x * xy;
                }
                if (k >= 1) {                        // row B taps 0..10
                    const v2f w = pw[(k - 1) < 6 ? (k - 1) : 11 - k];
                    uvB += w * v2;
                    qqB += w * q2;
                    xyB += w.x * xy;
                }
            }
            const int rA = 2 * r2, rB = 2 * r2 + 1;
            *(v2f*)&pA[rA][2 * c] = uvA;   *(v2f*)&pA[rB][2 * c] = uvB;
            *(v2f*)&pB_[rA][2 * c] = qqA;  *(v2f*)&pB_[rB][2 * c] = qqB;
            pC_[rA][c] = xyA;              pC_[rB][c] = xyB;
        }
        __syncthreads();

        // ---- phase 2: horizontal 11-tap blur (packed) + SSIM.
        // Window pairs P[p] for p=0..13 live in 7 aligned b128 loads;
        // output j uses P[j..j+10] with symmetric weights 0,1,2,3,4,5,4,3,2,1,0.
#define PCONV(R0, R1, R2, R3, a0, a1, a2, a3, a4, a5, a6)                       \
    R0 += pw[0]*LOWP(a0); R0 += pw[1]*HIGHP(a0); R0 += pw[2]*LOWP(a1);          \
    R0 += pw[3]*HIGHP(a1); R0 += pw[4]*LOWP(a2); R0 += pw[5]*HIGHP(a2);         \
    R0 += pw[4]*LOWP(a3); R0 += pw[3]*HIGHP(a3); R0 += pw[2]*LOWP(a4);          \
    R0 += pw[1]*HIGHP(a4); R0 += pw[0]*LOWP(a5);                                \
    R1 += pw[0]*HIGHP(a0); R1 += pw[1]*LOWP(a1); R1 += pw[2]*HIGHP(a1);         \
    R1 += pw[3]*LOWP(a2); R1 += pw[4]*HIGHP(a2); R1 += pw[5]*LOWP(a3);          \
    R1 += pw[4]*HIGHP(a3); R1 += pw[3]*LOWP(a4); R1 += pw[2]*HIGHP(a4);         \
    R1 += pw[1]*LOWP(a5); R1 += pw[0]*HIGHP(a5);                                \
    R2 += pw[0]*LOWP(a1); R2 += pw[1]*HIGHP(a1); R2 += pw[2]*LOWP(a2);          \
    R2 += pw[3]*HIGHP(a2); R2 += pw[4]*LOWP(a3); R2 += pw[5]*HIGHP(a3);         \
    R2 += pw[4]*LOWP(a4); R2 += pw[3]*HIGHP(a4); R2 += pw[2]*LOWP(a5);          \
    R2 += pw[1]*HIGHP(a5); R2 += pw[0]*LOWP(a6);                                \
    R3 += pw[0]*HIGHP(a1); R3 += pw[1]*LOWP(a2); R3 += pw[2]*HIGHP(a2);         \
    R3 += pw[3]*LOWP(a3); R3 += pw[4]*HIGHP(a3); R3 += pw[5]*LOWP(a4);          \
    R3 += pw[4]*HIGHP(a4); R3 += pw[3]*LOWP(a5); R3 += pw[2]*HIGHP(a5);         \
    R3 += pw[1]*LOWP(a6); R3 += pw[0]*HIGHP(a6);

#define SCONV(R, S0, S1, S2, S3, S4, S5, S6, S7, S8, S9, S10)                   \
    R += pw[0].x*S0; R += pw[1].x*S1; R += pw[2].x*S2; R += pw[3].x*S3;         \
    R += pw[4].x*S4; R += pw[5].x*S5; R += pw[4].x*S6; R += pw[3].x*S7;         \
    R += pw[2].x*S8; R += pw[1].x*S9; R += pw[0].x*S10;

        v2f rUV0 = {0.f, 0.f}, rUV1 = {0.f, 0.f}, rUV2 = {0.f, 0.f}, rUV3 = {0.f, 0.f};
        {
            const float* rowA = &pA[p2_r][8 * p2_m];
            const v4f a0 = *(const v4f*)(rowA + 0);
            const v4f a1 = *(const v4f*)(rowA + 4);
            const v4f a2 = *(const v4f*)(rowA + 8);
            const v4f a3 = *(const v4f*)(rowA + 12);
            const v4f a4 = *(const v4f*)(rowA + 16);
            const v4f a5 = *(const v4f*)(rowA + 20);
            const v4f a6 = *(const v4f*)(rowA + 24);
            PCONV(rUV0, rUV1, rUV2, rUV3, a0, a1, a2, a3, a4, a5, a6)
        }
        v2f rQQ0 = {0.f, 0.f}, rQQ1 = {0.f, 0.f}, rQQ2 = {0.f, 0.f}, rQQ3 = {0.f, 0.f};
        {
            const float* rowB = &pB_[p2_r][8 * p2_m];
            const v4f a0 = *(const v4f*)(rowB + 0);
            const v4f a1 = *(const v4f*)(rowB + 4);
            const v4f a2 = *(const v4f*)(rowB + 8);
            const v4f a3 = *(const v4f*)(rowB + 12);
            const v4f a4 = *(const v4f*)(rowB + 16);
            const v4f a5 = *(const v4f*)(rowB + 20);
            const v4f a6 = *(const v4f*)(rowB + 24);
            PCONV(rQQ0, rQQ1, rQQ2, rQQ3, a0, a1, a2, a3, a4, a5, a6)
        }
        float rC0 = 0.f, rC1 = 0.f, rC2 = 0.f, rC3 = 0.f;
        {
            const float* rowC = &pC_[p2_r][4 * p2_m];
            const v4f c0 = *(const v4f*)(rowC + 0);
            const v4f c1 = *(const v4f*)(rowC + 4);
            const v4f c2 = *(const v4f*)(rowC + 8);
            const v4f c3 = *(const v4f*)(rowC + 12);
            const float e0 = c0.x, e1 = c0.y, e2 = c0.z, e3 = c0.w;
            const float e4 = c1.x, e5 = c1.y, e6 = c1.z, e7 = c1.w;
            const float e8 = c2.x, e9 = c2.y, e10 = c2.z, e11 = c2.w;
            const float e12 = c3.x, e13 = c3.y;
            SCONV(rC0, e0, e1, e2, e3, e4, e5, e6, e7, e8, e9, e10)
            SCONV(rC1, e1, e2, e3, e4, e5, e6, e7, e8, e9, e10, e11)
            SCONV(rC2, e2, e3, e4, e5, e6, e7, e8, e9, e10, e11, e12)
            SCONV(rC3, e3, e4, e5, e6, e7, e8, e9, e10, e11, e12, e13)
        }

        float4 o4;
#pragma unroll
        for (int j = 0; j < 4; ++j) {
            const v2f uvj = (j == 0) ? rUV0 : (j == 1) ? rUV1 : (j == 2) ? rUV2 : rUV3;
            const v2f qqj = (j == 0) ? rQQ0 : (j == 1) ? rQQ1 : (j == 2) ? rQQ2 : rQQ3;
            const float uxy = (j == 0) ? rC0 : (j == 1) ? rC1 : (j == 2) ? rC2 : rC3;
            const float ux = uvj.x, uy = uvj.y;
            const float uxx = qqj.x, uyy = qqj.y;
            const float vx  = uxx - ux * ux;
            const float vy  = uyy - uy * uy;
            const float vxy = uxy - ux * uy;
            const float a1s = 2.f * ux * uy + SSIM_C1;
            const float a2s = 2.f * vxy + SSIM_C2;
            const float b1s = ux * ux + uy * uy + SSIM_C1;
            const float b2s = vx + vy + SSIM_C2;
            (&o4.x)[j] = (a1s * a2s) * __builtin_amdgcn_rcpf(b1s * b2s);
        }
        *(float4*)(op + (size_t)(tile_r + s0 + p2_r) * WW + (tile_c + 4 * p2_m)) = o4;
        __syncthreads();   // LDS reused by next slab
#undef PCONV
#undef SCONV
    };

    if (interior) {
        run_slab(0,    std::true_type{});
        run_slab(SLAB, std::true_type{});
    } else {
        run_slab(0,    std::false_type{});
        run_slab(SLAB, std::false_type{});
    }
}

extern "C" void kernel_launch(void* const* d_in, const int* in_sizes, int n_in,
                              void* d_out, int out_size, void* d_ws, size_t ws_size,
                              hipStream_t stream) {
    const float* x    = (const float*)d_in[0];
    const float* y    = (const float*)d_in[1];
    const float* kern = (const float*)d_in[2];
    float* out = (float*)d_out;

    const int nplanes = in_sizes[0] / (HH * WW);            // 48
    const int nblocks = nplanes * (HH / TH) * (WW / TW);    // 6144

    ssim_fused<<<dim3(nblocks), dim3(NTHREADS), 0, stream>>>(x, y, kern, out);
}